// Round 1
// baseline (300.224 us; speedup 1.0000x reference)
//
#include <hip/hip_runtime.h>
#include <hip/hip_bf16.h>

using bf16 = __hip_bfloat16;
typedef float f32x4 __attribute__((ext_vector_type(4)));
typedef short s16x8 __attribute__((ext_vector_type(8)));

#define B_N   8
#define C_N   512
#define HW_N  1024
#define LC_N  1024
#define HID_N 512
#define NHEAD 8
#define DHEAD 64
#define EPSN  1e-6f

__device__ __forceinline__ f32x4 mfma16(s16x8 a, s16x8 b, f32x4 c) {
  return __builtin_amdgcn_mfma_f32_16x16x32_bf16(a, b, c, 0, 0, 0);
}
__device__ __forceinline__ void gload_lds16(const void* g, void* l) {
  __builtin_amdgcn_global_load_lds((const __attribute__((address_space(1))) void*)g,
                                   (__attribute__((address_space(3))) void*)l, 16, 0, 0);
}
__device__ __forceinline__ s16x8 ld8(const bf16* p) {
  return *reinterpret_cast<const s16x8*>(p);
}

// ---------------- K0: weight prep (fold g, convert to bf16) ----------------
__global__ __launch_bounds__(256) void prep_weights(
    const float* __restrict__ Wq, const float* __restrict__ Wkv,
    const float* __restrict__ Wo, const float* __restrict__ g,
    bf16* __restrict__ Wqg, bf16* __restrict__ Wkvg, bf16* __restrict__ Wob)
{
  int idx = blockIdx.x * 256 + threadIdx.x;           // 0 .. 1048575
  const int NQ = 512 * 512, NKV = 1024 * 512;
  if (idx < NQ) {
    Wqg[idx] = __float2bfloat16(Wq[idx] * g[idx & 511]);
  } else if (idx < NQ + NKV) {
    int j = idx - NQ;
    Wkvg[j] = __float2bfloat16(Wkv[j] * g[j & 511]);
  } else {
    int j = idx - NQ - NKV;
    Wob[j] = __float2bfloat16(Wo[j]);
  }
}

// ---------------- K1: per-pixel rstd of x over channels ----------------
__global__ __launch_bounds__(256) void rstd_ch_kernel(
    const float* __restrict__ x, float* __restrict__ rstd)
{
  __shared__ float part[4][64];
  int tp = threadIdx.x & 63, tc = threadIdx.x >> 6;
  int gp = blockIdx.x * 64 + tp;                      // 0..8191
  int b = gp >> 10, p = gp & 1023;
  const float* xb = x + (long)b * C_N * HW_N + p;
  float s = 0.f;
  for (int c = tc * 128; c < tc * 128 + 128; ++c) {
    float v = xb[(long)c * HW_N];
    s += v * v;
  }
  part[tc][tp] = s;
  __syncthreads();
  if (tc == 0) {
    float tot = part[0][tp] + part[1][tp] + part[2][tp] + part[3][tp];
    rstd[gp] = rsqrtf(tot * (1.0f / C_N) + EPSN);
  }
}

// ---------------- K2: xbf[b][p][c] = bf16(x[b][c][p] * rstd) (transpose) ----------------
__global__ __launch_bounds__(256) void xbf_kernel(
    const float* __restrict__ x, const float* __restrict__ rstd, bf16* __restrict__ xbf)
{
  __shared__ float tile[32][33];
  int b = blockIdx.z, c0 = blockIdx.y * 32, p0 = blockIdx.x * 32;
  int tx = threadIdx.x & 31, ty = threadIdx.x >> 5;   // ty 0..7
#pragma unroll
  for (int j = 0; j < 4; ++j) {
    int c = ty + j * 8;
    tile[c][tx] = x[((long)b * C_N + c0 + c) * HW_N + p0 + tx];
  }
  __syncthreads();
#pragma unroll
  for (int j = 0; j < 4; ++j) {
    int p = ty + j * 8;
    float r = rstd[b * HW_N + p0 + p];
    xbf[((long)b * HW_N + p0 + p) * C_N + c0 + tx] = __float2bfloat16(tile[tx][p] * r);
  }
}

// ---------------- K3: context RMSNorm -> bf16 (rows contiguous) ----------------
__global__ __launch_bounds__(256) void ctxnorm_kernel(
    const float* __restrict__ ctx, bf16* __restrict__ cnbf)
{
  int row = blockIdx.x * 4 + (threadIdx.x >> 6);      // 0..8191
  int lane = threadIdx.x & 63;
  const float* cr = ctx + (long)row * C_N;
  float4 v0 = ((const float4*)cr)[lane * 2];
  float4 v1 = ((const float4*)cr)[lane * 2 + 1];
  float s = v0.x*v0.x + v0.y*v0.y + v0.z*v0.z + v0.w*v0.w
          + v1.x*v1.x + v1.y*v1.y + v1.z*v1.z + v1.w*v1.w;
#pragma unroll
  for (int m = 1; m < 64; m <<= 1) s += __shfl_xor(s, m);
  float r = rsqrtf(s * (1.0f / C_N) + EPSN);
  bf16 tmp[8];
  tmp[0] = __float2bfloat16(v0.x * r); tmp[1] = __float2bfloat16(v0.y * r);
  tmp[2] = __float2bfloat16(v0.z * r); tmp[3] = __float2bfloat16(v0.w * r);
  tmp[4] = __float2bfloat16(v1.x * r); tmp[5] = __float2bfloat16(v1.y * r);
  tmp[6] = __float2bfloat16(v1.z * r); tmp[7] = __float2bfloat16(v1.w * r);
  *reinterpret_cast<s16x8*>(cnbf + (long)row * C_N + lane * 8) =
      *reinterpret_cast<const s16x8*>(tmp);
}

// ---------------- K4: generic NT MFMA GEMM: C[M,N] = A[M,K] * B[N,K]^T ----------------
// MODE 0: bf16 out with scale (Q).  MODE 1: bf16 out + vT transposed copy of V half (KV).
// MODE 2: fp32 out (projection).
template<int MODE>
__global__ __launch_bounds__(256)
void gemm_nt(const bf16* __restrict__ A, const bf16* __restrict__ W,
             void* __restrict__ outp, bf16* __restrict__ vT,
             int M, int N, int K, float scale, long strideA, long strideOut)
{
  __shared__ bf16 sA[128 * 32];
  __shared__ bf16 sB[128 * 32];
  const int t = threadIdx.x;
  const int b = blockIdx.z;
  const int m0 = blockIdx.y * 128;
  const int n0 = blockIdx.x * 128;
  const bf16* Ab = A + (long)b * strideA;
  const int lane = t & 63;
  const int w = t >> 6;
  const int wm = (w >> 1) * 64, wn = (w & 1) * 64;
  const int lr = lane & 15, hi = lane >> 4;
  const int r = t >> 2, seg = t & 3;

  f32x4 acc[4][4] = {};

  for (int k0 = 0; k0 < K; k0 += 32) {
    gload_lds16(Ab + (long)(m0 + r) * K + k0 + seg * 8,        &sA[r * 32 + seg * 8]);
    gload_lds16(Ab + (long)(m0 + 64 + r) * K + k0 + seg * 8,   &sA[(64 + r) * 32 + seg * 8]);
    gload_lds16(W  + (long)(n0 + r) * K + k0 + seg * 8,        &sB[r * 32 + seg * 8]);
    gload_lds16(W  + (long)(n0 + 64 + r) * K + k0 + seg * 8,   &sB[(64 + r) * 32 + seg * 8]);
    __syncthreads();
    s16x8 af[4], bfr[4];
#pragma unroll
    for (int mi = 0; mi < 4; ++mi)
      af[mi] = *reinterpret_cast<const s16x8*>(&sA[(wm + mi * 16 + lr) * 32 + hi * 8]);
#pragma unroll
    for (int ni = 0; ni < 4; ++ni)
      bfr[ni] = *reinterpret_cast<const s16x8*>(&sB[(wn + ni * 16 + lr) * 32 + hi * 8]);
#pragma unroll
    for (int mi = 0; mi < 4; ++mi)
#pragma unroll
      for (int ni = 0; ni < 4; ++ni)
        acc[mi][ni] = mfma16(af[mi], bfr[ni], acc[mi][ni]);
    __syncthreads();
  }

#pragma unroll
  for (int mi = 0; mi < 4; ++mi) {
#pragma unroll
    for (int ni = 0; ni < 4; ++ni) {
#pragma unroll
      for (int rr = 0; rr < 4; ++rr) {
        int row = m0 + wm + mi * 16 + hi * 4 + rr;   // M index
        int col = n0 + wn + ni * 16 + lr;            // N index
        float v = acc[mi][ni][rr] * scale;
        if (MODE == 2) {
          ((float*)outp)[(long)b * strideOut + (long)row * N + col] = v;
        } else {
          ((bf16*)outp)[(long)b * strideOut + (long)row * N + col] = __float2bfloat16(v);
          if (MODE == 1 && col >= HID_N) {
            vT[((long)b * HID_N + (col - HID_N)) * LC_N + row] = __float2bfloat16(v);
          }
        }
      }
    }
  }
}

// ---------------- K5: fused flash attention (1 wave = 16 query rows) ----------------
__global__ __launch_bounds__(256)
void attn_fused(const bf16* __restrict__ qbf, const bf16* __restrict__ kvbf,
                const bf16* __restrict__ vT, bf16* __restrict__ attno)
{
  __shared__ bf16 Pl[4][16 * 32];
  const int t = threadIdx.x;
  const int wv = t >> 6, lane = t & 63;
  const int lr = lane & 15, hi = lane >> 4;
  const int bh = blockIdx.y, b = bh >> 3, h = bh & 7;
  const int p0 = blockIdx.x * 64 + wv * 16;

  const bf16* qrow = qbf + ((long)b * HW_N + p0 + lr) * HID_N + h * DHEAD;
  s16x8 qa0 = ld8(qrow + hi * 8);
  s16x8 qa1 = ld8(qrow + 32 + hi * 8);

  float mold[4] = {-INFINITY, -INFINITY, -INFINITY, -INFINITY};
  float lsum[4] = {0.f, 0.f, 0.f, 0.f};
  f32x4 o[4] = {};

  const bf16* kbase = kvbf + (long)b * LC_N * 1024 + h * DHEAD;
  const bf16* vbase = vT + ((long)b * HID_N + h * DHEAD) * LC_N;
  bf16* Pw = Pl[wv];

  for (int l0 = 0; l0 < LC_N; l0 += 32) {
    f32x4 s0 = {}, s1 = {};
    {
      const bf16* k0p = kbase + (long)(l0 + lr) * 1024;
      const bf16* k1p = kbase + (long)(l0 + 16 + lr) * 1024;
      s16x8 kf00 = ld8(k0p + hi * 8);
      s16x8 kf01 = ld8(k0p + 32 + hi * 8);
      s16x8 kf10 = ld8(k1p + hi * 8);
      s16x8 kf11 = ld8(k1p + 32 + hi * 8);
      s0 = mfma16(qa0, kf00, s0);
      s0 = mfma16(qa1, kf01, s0);
      s1 = mfma16(qa0, kf10, s1);
      s1 = mfma16(qa1, kf11, s1);
    }
    float alpha[4];
#pragma unroll
    for (int rr = 0; rr < 4; ++rr) {
      float vmax = fmaxf(s0[rr], s1[rr]);
#pragma unroll
      for (int m = 1; m < 16; m <<= 1) vmax = fmaxf(vmax, __shfl_xor(vmax, m));
      float mnew = fmaxf(mold[rr], vmax);
      float a = __expf(mold[rr] - mnew);
      float p0v = __expf(s0[rr] - mnew);
      float p1v = __expf(s1[rr] - mnew);
      float rs = p0v + p1v;
#pragma unroll
      for (int m = 1; m < 16; m <<= 1) rs += __shfl_xor(rs, m);
      lsum[rr] = lsum[rr] * a + rs;
      mold[rr] = mnew;
      alpha[rr] = a;
      Pw[(hi * 4 + rr) * 32 + lr]      = __float2bfloat16(p0v);
      Pw[(hi * 4 + rr) * 32 + 16 + lr] = __float2bfloat16(p1v);
    }
#pragma unroll
    for (int ni = 0; ni < 4; ++ni)
#pragma unroll
      for (int rr = 0; rr < 4; ++rr) o[ni][rr] *= alpha[rr];

    s16x8 pa = *reinterpret_cast<const s16x8*>(&Pw[lr * 32 + hi * 8]);
#pragma unroll
    for (int ni = 0; ni < 4; ++ni) {
      s16x8 vf = ld8(vbase + (long)(ni * 16 + lr) * LC_N + l0 + hi * 8);
      o[ni] = mfma16(pa, vf, o[ni]);
    }
  }
#pragma unroll
  for (int ni = 0; ni < 4; ++ni)
#pragma unroll
    for (int rr = 0; rr < 4; ++rr) {
      float v = o[ni][rr] / lsum[rr];
      attno[((long)b * HW_N + p0 + hi * 4 + rr) * HID_N + h * DHEAD + ni * 16 + lr] =
          __float2bfloat16(v);
    }
}

// ---------------- K7: y row stats (with bias) ----------------
__global__ __launch_bounds__(256) void ystats_kernel(
    const float* __restrict__ ytmp, const float* __restrict__ bo, float* __restrict__ rstdy)
{
  int row = blockIdx.x * 4 + (threadIdx.x >> 6);      // 0..8191
  int lane = threadIdx.x & 63;
  const float* yr = ytmp + (long)row * C_N;
  float s = 0.f;
#pragma unroll
  for (int j = 0; j < 2; ++j) {
    float4 v = ((const float4*)yr)[lane * 2 + j];
    float4 bb = ((const float4*)bo)[lane * 2 + j];
    v.x += bb.x; v.y += bb.y; v.z += bb.z; v.w += bb.w;
    s += v.x*v.x + v.y*v.y + v.z*v.z + v.w*v.w;
  }
#pragma unroll
  for (int m = 1; m < 64; m <<= 1) s += __shfl_xor(s, m);
  if (lane == 0) { }
  rstdy[row] = rsqrtf(s * (1.0f / C_N) + EPSN);
}

// ---------------- K8: final transpose + bias + norm + residual ----------------
__global__ __launch_bounds__(256) void final_kernel(
    const float* __restrict__ ytmp, const float* __restrict__ bo,
    const float* __restrict__ g2, const float* __restrict__ rstdy,
    const float* __restrict__ x, float* __restrict__ out)
{
  __shared__ float tile[32][33];
  int b = blockIdx.z, c0 = blockIdx.y * 32, p0 = blockIdx.x * 32;
  int tx = threadIdx.x & 31, ty = threadIdx.x >> 5;
#pragma unroll
  for (int j = 0; j < 4; ++j) {
    int p = ty + j * 8;
    tile[p][tx] = ytmp[((long)b * HW_N + p0 + p) * C_N + c0 + tx] + bo[c0 + tx];
  }
  __syncthreads();
#pragma unroll
  for (int j = 0; j < 4; ++j) {
    int c = ty + j * 8;
    long oidx = ((long)b * C_N + c0 + c) * HW_N + p0 + tx;
    out[oidx] = tile[tx][c] * rstdy[b * HW_N + p0 + tx] * g2[c0 + c] + x[oidx];
  }
}

// ---------------- launch ----------------
extern "C" void kernel_launch(void* const* d_in, const int* in_sizes, int n_in,
                              void* d_out, int out_size, void* d_ws, size_t ws_size,
                              hipStream_t stream) {
  const float* x   = (const float*)d_in[0];
  const float* ctx = (const float*)d_in[1];
  const float* Wq  = (const float*)d_in[2];
  const float* Wkv = (const float*)d_in[3];
  const float* Wo  = (const float*)d_in[4];
  const float* bo  = (const float*)d_in[5];
  const float* g   = (const float*)d_in[6];
  const float* g2  = (const float*)d_in[7];
  float* out = (float*)d_out;

  char* ws = (char*)d_ws;
  // byte offsets (all 256-aligned)
  bf16*  Wqg   = (bf16*)(ws + 0);          //  512*512*2  = 524288
  bf16*  Wkvg  = (bf16*)(ws + 524288);     // 1024*512*2  = 1048576
  bf16*  Wob   = (bf16*)(ws + 1572864);    //  512*512*2  = 524288
  float* rstdx = (float*)(ws + 2097152);   // 8192*4      = 32768
  float* rstdy = (float*)(ws + 2129920);   // 8192*4      = 32768
  bf16*  xbf   = (bf16*)(ws + 2162688);    // 8*1024*512*2 = 8388608
  bf16*  cnbf  = (bf16*)(ws + 10551296);   // 8388608
  bf16*  qbf   = (bf16*)(ws + 18939904);   // 8388608
  bf16*  kvbf  = (bf16*)(ws + 27328512);   // 8*1024*1024*2 = 16777216
  bf16*  vT    = (bf16*)(ws + 44105728);   // 8388608
  bf16*  attno = (bf16*)(ws + 52494336);   // 8388608
  // ytmp aliases xbf+cnbf (both dead after the Q/KV GEMMs)
  float* ytmp  = (float*)(ws + 2162688);   // 8*1024*512*4 = 16777216
  // total footprint: 60882944 bytes (~58 MB)

  prep_weights<<<4096, 256, 0, stream>>>(Wq, Wkv, Wo, g, Wqg, Wkvg, Wob);
  rstd_ch_kernel<<<128, 256, 0, stream>>>(x, rstdx);
  xbf_kernel<<<dim3(32, 16, 8), 256, 0, stream>>>(x, rstdx, xbf);
  ctxnorm_kernel<<<2048, 256, 0, stream>>>(ctx, cnbf);

  // Q = xn @ Wq^T, scaled by 1/8    -> qbf[b][p][512]
  gemm_nt<0><<<dim3(4, 8, 8), 256, 0, stream>>>(
      xbf, Wqg, qbf, nullptr, HW_N, HID_N, C_N, 0.125f,
      (long)HW_N * C_N, (long)HW_N * HID_N);
  // KV = cn @ Wkv^T                 -> kvbf[b][l][1024] (+ vT)
  gemm_nt<1><<<dim3(8, 8, 8), 256, 0, stream>>>(
      cnbf, Wkvg, kvbf, vT, LC_N, 2 * HID_N, C_N, 1.0f,
      (long)LC_N * C_N, (long)LC_N * 2 * HID_N);

  attn_fused<<<dim3(16, 64), 256, 0, stream>>>(qbf, kvbf, vT, attno);

  // y = attno @ Wo^T  -> ytmp[b][p][512] (fp32)
  gemm_nt<2><<<dim3(4, 8, 8), 256, 0, stream>>>(
      attno, Wob, ytmp, nullptr, HW_N, C_N, HID_N, 1.0f,
      (long)HW_N * HID_N, (long)HW_N * C_N);

  ystats_kernel<<<2048, 256, 0, stream>>>(ytmp, bo, rstdy);
  final_kernel<<<dim3(32, 16, 8), 256, 0, stream>>>(ytmp, bo, g2, rstdy, x, out);
}

// Round 2
// 243.704 us; speedup vs baseline: 1.2319x; 1.2319x over previous
//
#include <hip/hip_runtime.h>
#include <hip/hip_bf16.h>

using bf16 = __hip_bfloat16;
typedef float f32x4 __attribute__((ext_vector_type(4)));
typedef short s16x8 __attribute__((ext_vector_type(8)));
typedef short s16x4 __attribute__((ext_vector_type(4)));

#define B_N   8
#define C_N   512
#define HW_N  1024
#define LC_N  1024
#define HID_N 512
#define NHEAD 8
#define DHEAD 64
#define EPSN  1e-6f

__device__ __forceinline__ f32x4 mfma16(s16x8 a, s16x8 b, f32x4 c) {
  return __builtin_amdgcn_mfma_f32_16x16x32_bf16(a, b, c, 0, 0, 0);
}
__device__ __forceinline__ void gload_lds16(const void* g, void* l) {
  __builtin_amdgcn_global_load_lds((const __attribute__((address_space(1))) void*)g,
                                   (__attribute__((address_space(3))) void*)l, 16, 0, 0);
}
__device__ __forceinline__ s16x8 ld8(const bf16* p) {
  return *reinterpret_cast<const s16x8*>(p);
}
__device__ __forceinline__ unsigned short bfbits(float f) {
  return __builtin_bit_cast(unsigned short, __float2bfloat16(f));
}

// ---------------- K0: weight prep (fold g, convert to bf16) ----------------
__global__ __launch_bounds__(256) void prep_weights(
    const float* __restrict__ Wq, const float* __restrict__ Wkv,
    const float* __restrict__ Wo, const float* __restrict__ g,
    bf16* __restrict__ Wqg, bf16* __restrict__ Wkvg, bf16* __restrict__ Wob)
{
  int idx = blockIdx.x * 256 + threadIdx.x;           // 0 .. 1048575
  const int NQ = 512 * 512, NKV = 1024 * 512;
  if (idx < NQ) {
    Wqg[idx] = __float2bfloat16(Wq[idx] * g[idx & 511]);
  } else if (idx < NQ + NKV) {
    int j = idx - NQ;
    Wkvg[j] = __float2bfloat16(Wkv[j] * g[j & 511]);
  } else {
    int j = idx - NQ - NKV;
    Wob[j] = __float2bfloat16(Wo[j]);
  }
}

// ---------------- K1: per-pixel rstd of x over channels ----------------
__global__ __launch_bounds__(256) void rstd_ch_kernel(
    const float* __restrict__ x, float* __restrict__ rstd)
{
  __shared__ float part[4][64];
  int tp = threadIdx.x & 63, tc = threadIdx.x >> 6;
  int gp = blockIdx.x * 64 + tp;                      // 0..8191
  int b = gp >> 10, p = gp & 1023;
  const float* xb = x + (long)b * C_N * HW_N + p;
  float s = 0.f;
  for (int c = tc * 128; c < tc * 128 + 128; ++c) {
    float v = xb[(long)c * HW_N];
    s += v * v;
  }
  part[tc][tp] = s;
  __syncthreads();
  if (tc == 0) {
    float tot = part[0][tp] + part[1][tp] + part[2][tp] + part[3][tp];
    rstd[gp] = rsqrtf(tot * (1.0f / C_N) + EPSN);
  }
}

// ---------------- K2: xbf[b][p][c] = bf16(x[b][c][p] * rstd) (transpose) ----------------
__global__ __launch_bounds__(256) void xbf_kernel(
    const float* __restrict__ x, const float* __restrict__ rstd, bf16* __restrict__ xbf)
{
  __shared__ float tile[32][33];
  int b = blockIdx.z, c0 = blockIdx.y * 32, p0 = blockIdx.x * 32;
  int tx = threadIdx.x & 31, ty = threadIdx.x >> 5;   // ty 0..7
#pragma unroll
  for (int j = 0; j < 4; ++j) {
    int c = ty + j * 8;
    tile[c][tx] = x[((long)b * C_N + c0 + c) * HW_N + p0 + tx];
  }
  __syncthreads();
#pragma unroll
  for (int j = 0; j < 4; ++j) {
    int p = ty + j * 8;
    float r = rstd[b * HW_N + p0 + p];
    xbf[((long)b * HW_N + p0 + p) * C_N + c0 + tx] = __float2bfloat16(tile[tx][p] * r);
  }
}

// ---------------- K3: context RMSNorm -> bf16 (rows contiguous) ----------------
__global__ __launch_bounds__(256) void ctxnorm_kernel(
    const float* __restrict__ ctx, bf16* __restrict__ cnbf)
{
  int row = blockIdx.x * 4 + (threadIdx.x >> 6);      // 0..8191
  int lane = threadIdx.x & 63;
  const float* cr = ctx + (long)row * C_N;
  float4 v0 = ((const float4*)cr)[lane * 2];
  float4 v1 = ((const float4*)cr)[lane * 2 + 1];
  float s = v0.x*v0.x + v0.y*v0.y + v0.z*v0.z + v0.w*v0.w
          + v1.x*v1.x + v1.y*v1.y + v1.z*v1.z + v1.w*v1.w;
#pragma unroll
  for (int m = 1; m < 64; m <<= 1) s += __shfl_xor(s, m);
  float r = rsqrtf(s * (1.0f / C_N) + EPSN);
  bf16 tmp[8];
  tmp[0] = __float2bfloat16(v0.x * r); tmp[1] = __float2bfloat16(v0.y * r);
  tmp[2] = __float2bfloat16(v0.z * r); tmp[3] = __float2bfloat16(v0.w * r);
  tmp[4] = __float2bfloat16(v1.x * r); tmp[5] = __float2bfloat16(v1.y * r);
  tmp[6] = __float2bfloat16(v1.z * r); tmp[7] = __float2bfloat16(v1.w * r);
  *reinterpret_cast<s16x8*>(cnbf + (long)row * C_N + lane * 8) =
      *reinterpret_cast<const s16x8*>(tmp);
}

// ---------------- K4: generic NT MFMA GEMM: C[M,N] = A[M,K] * B[N,K]^T ----------------
template<int MODE>
__global__ __launch_bounds__(256)
void gemm_nt(const bf16* __restrict__ A, const bf16* __restrict__ W,
             void* __restrict__ outp, bf16* __restrict__ vT,
             int M, int N, int K, float scale, long strideA, long strideOut)
{
  __shared__ bf16 sA[128 * 32];
  __shared__ bf16 sB[128 * 32];
  const int t = threadIdx.x;
  const int b = blockIdx.z;
  const int m0 = blockIdx.y * 128;
  const int n0 = blockIdx.x * 128;
  const bf16* Ab = A + (long)b * strideA;
  const int lane = t & 63;
  const int w = t >> 6;
  const int wm = (w >> 1) * 64, wn = (w & 1) * 64;
  const int lr = lane & 15, hi = lane >> 4;
  const int r = t >> 2, seg = t & 3;

  f32x4 acc[4][4] = {};

  for (int k0 = 0; k0 < K; k0 += 32) {
    gload_lds16(Ab + (long)(m0 + r) * K + k0 + seg * 8,        &sA[r * 32 + seg * 8]);
    gload_lds16(Ab + (long)(m0 + 64 + r) * K + k0 + seg * 8,   &sA[(64 + r) * 32 + seg * 8]);
    gload_lds16(W  + (long)(n0 + r) * K + k0 + seg * 8,        &sB[r * 32 + seg * 8]);
    gload_lds16(W  + (long)(n0 + 64 + r) * K + k0 + seg * 8,   &sB[(64 + r) * 32 + seg * 8]);
    __syncthreads();
    s16x8 af[4], bfr[4];
#pragma unroll
    for (int mi = 0; mi < 4; ++mi)
      af[mi] = *reinterpret_cast<const s16x8*>(&sA[(wm + mi * 16 + lr) * 32 + hi * 8]);
#pragma unroll
    for (int ni = 0; ni < 4; ++ni)
      bfr[ni] = *reinterpret_cast<const s16x8*>(&sB[(wn + ni * 16 + lr) * 32 + hi * 8]);
#pragma unroll
    for (int mi = 0; mi < 4; ++mi)
#pragma unroll
      for (int ni = 0; ni < 4; ++ni)
        acc[mi][ni] = mfma16(af[mi], bfr[ni], acc[mi][ni]);
    __syncthreads();
  }

#pragma unroll
  for (int mi = 0; mi < 4; ++mi) {
#pragma unroll
    for (int ni = 0; ni < 4; ++ni) {
#pragma unroll
      for (int rr = 0; rr < 4; ++rr) {
        int row = m0 + wm + mi * 16 + (lane >> 4) * 4 + rr;
        int col = n0 + wn + ni * 16 + lr;
        float v = acc[mi][ni][rr] * scale;
        if (MODE == 2) {
          ((float*)outp)[(long)b * strideOut + (long)row * N + col] = v;
        } else {
          ((bf16*)outp)[(long)b * strideOut + (long)row * N + col] = __float2bfloat16(v);
          if (MODE == 1 && col >= HID_N) {
            vT[((long)b * HID_N + (col - HID_N)) * LC_N + row] = __float2bfloat16(v);
          }
        }
      }
    }
  }
}

// ---------------- K5: fused flash attention (1 wave = 32 query rows, 64-key blocks) ----
// Swapped QK^T: st = mfma(Kfrag, Qfrag) -> lane holds S[key=kt*16+hi*4+rr][q=qt*16+lr].
// Defer-max (THR=8) + deferred per-lane lsum partials. Register-prefetched K/V.
__global__ __launch_bounds__(256)
void attn_fused(const bf16* __restrict__ qbf, const bf16* __restrict__ kvbf,
                const bf16* __restrict__ vT, bf16* __restrict__ attno)
{
  __shared__ bf16 Pl[4][32 * 72];                     // per-wave P tile, stride 72 (pad)
  const int t = threadIdx.x;
  const int wv = t >> 6, lane = t & 63;
  const int lr = lane & 15, hi = lane >> 4;
  const int hi8 = hi * 8, hi4 = hi * 4;
  const int bh = blockIdx.y, b = bh >> 3, h = bh & 7;
  const int q_base = blockIdx.x * 128 + wv * 32;

  // Q fragments [qt][c]: lane holds Q[q_base+qt*16+lr][c*32+hi*8 ..+7]
  s16x8 qf[2][2];
#pragma unroll
  for (int qt = 0; qt < 2; ++qt)
#pragma unroll
    for (int c = 0; c < 2; ++c)
      qf[qt][c] = ld8(qbf + ((long)b * HW_N + q_base + qt * 16 + lr) * HID_N
                          + h * DHEAD + c * 32 + hi8);

  const bf16* kbase = kvbf + (long)b * LC_N * 1024 + h * DHEAD;        // row stride 1024
  const bf16* vbase = vT + ((long)b * HID_N + h * DHEAD) * (long)LC_N; // [d][l]
  bf16* Pw = Pl[wv];

  float m[2] = {-1e30f, -1e30f};
  float lsum[2] = {0.f, 0.f};
  f32x4 o[2][4] = {};

  s16x8 kf[4][2];   // K frags [kt][c]: K[l0+kt*16+lr][c*32+hi*8..]
  s16x8 vf[4][2];   // Vt frags [dt][c]: Vt[h*64+dt*16+lr][l0+c*32+hi*8..]

  // prologue: K(0)
#pragma unroll
  for (int kt = 0; kt < 4; ++kt)
#pragma unroll
    for (int c = 0; c < 2; ++c)
      kf[kt][c] = ld8(kbase + (long)(kt * 16 + lr) * 1024 + c * 32 + hi8);

#pragma unroll 1
  for (int l0 = 0; l0 < LC_N; l0 += 64) {
    // issue V(l0) loads (consumed after softmax)
#pragma unroll
    for (int dt = 0; dt < 4; ++dt)
#pragma unroll
      for (int c = 0; c < 2; ++c)
        vf[dt][c] = ld8(vbase + (long)(dt * 16 + lr) * LC_N + l0 + c * 32 + hi8);

    // QK^T (swapped operands)
    f32x4 st[4][2] = {};
#pragma unroll
    for (int kt = 0; kt < 4; ++kt)
#pragma unroll
      for (int qt = 0; qt < 2; ++qt) {
        st[kt][qt] = mfma16(kf[kt][0], qf[qt][0], st[kt][qt]);
        st[kt][qt] = mfma16(kf[kt][1], qf[qt][1], st[kt][qt]);
      }

    // prefetch K(l0+64) into the now-consumed kf regs
    if (l0 + 64 < LC_N) {
#pragma unroll
      for (int kt = 0; kt < 4; ++kt)
#pragma unroll
        for (int c = 0; c < 2; ++c)
          kf[kt][c] = ld8(kbase + (long)(l0 + 64 + kt * 16 + lr) * 1024 + c * 32 + hi8);
    }

    // per-lane local max (no cross-lane reduce needed on the deferred path)
    float pmax[2];
#pragma unroll
    for (int qt = 0; qt < 2; ++qt) {
      float mx = st[0][qt][0];
#pragma unroll
      for (int kt = 0; kt < 4; ++kt)
#pragma unroll
        for (int rr = 0; rr < 4; ++rr)
          mx = fmaxf(mx, st[kt][qt][rr]);
      pmax[qt] = mx;
    }
    bool ok = (pmax[0] <= m[0] + 8.f) && (pmax[1] <= m[1] + 8.f);
    if (!__all(ok)) {
      // rare: full row-max across the 4 hi-lanes sharing this q-row, rescale o & lsum
#pragma unroll
      for (int qt = 0; qt < 2; ++qt) {
        float rm = pmax[qt];
        rm = fmaxf(rm, __shfl_xor(rm, 16));
        rm = fmaxf(rm, __shfl_xor(rm, 32));
        float mn = fmaxf(m[qt], rm);
        float al = __expf(m[qt] - mn);
        m[qt] = mn;
        lsum[qt] *= al;
        float arr[4];
#pragma unroll
        for (int rr = 0; rr < 4; ++rr) arr[rr] = __shfl(al, hi4 + rr);
#pragma unroll
        for (int dt = 0; dt < 4; ++dt)
#pragma unroll
          for (int rr = 0; rr < 4; ++rr) o[qt][dt][rr] *= arr[rr];
      }
    }

    // P = exp(s - m), pack to bf16, write per-wave LDS; accumulate per-lane lsum
#pragma unroll
    for (int qt = 0; qt < 2; ++qt) {
      float ls = 0.f;
#pragma unroll
      for (int kt = 0; kt < 4; ++kt) {
        float p0 = __expf(st[kt][qt][0] - m[qt]);
        float p1 = __expf(st[kt][qt][1] - m[qt]);
        float p2 = __expf(st[kt][qt][2] - m[qt]);
        float p3 = __expf(st[kt][qt][3] - m[qt]);
        ls += (p0 + p1) + (p2 + p3);
        s16x4 pk;
        pk[0] = (short)bfbits(p0); pk[1] = (short)bfbits(p1);
        pk[2] = (short)bfbits(p2); pk[3] = (short)bfbits(p3);
        *reinterpret_cast<s16x4*>(&Pw[(qt * 16 + lr) * 72 + kt * 16 + hi4]) = pk;
      }
      lsum[qt] += ls;
    }

    // PV: read P A-frags from LDS, multiply with prefetched Vt frags
#pragma unroll
    for (int qt = 0; qt < 2; ++qt) {
#pragma unroll
      for (int c = 0; c < 2; ++c) {
        s16x8 pa = *reinterpret_cast<const s16x8*>(&Pw[(qt * 16 + lr) * 72 + c * 32 + hi8]);
#pragma unroll
        for (int dt = 0; dt < 4; ++dt)
          o[qt][dt] = mfma16(pa, vf[dt][c], o[qt][dt]);
      }
    }
  }

  // epilogue: finish lsum (reduce the 4 hi-lane partials), normalize, store
#pragma unroll
  for (int qt = 0; qt < 2; ++qt) {
    float ls = lsum[qt];
    ls += __shfl_xor(ls, 16);
    ls += __shfl_xor(ls, 32);
    float linv[4];
#pragma unroll
    for (int rr = 0; rr < 4; ++rr) linv[rr] = 1.f / __shfl(ls, hi4 + rr);
#pragma unroll
    for (int dt = 0; dt < 4; ++dt)
#pragma unroll
      for (int rr = 0; rr < 4; ++rr)
        attno[((long)b * HW_N + q_base + qt * 16 + hi4 + rr) * HID_N
              + h * DHEAD + dt * 16 + lr] = __float2bfloat16(o[qt][dt][rr] * linv[rr]);
  }
}

// ---------------- K7: y row stats (with bias) ----------------
__global__ __launch_bounds__(256) void ystats_kernel(
    const float* __restrict__ ytmp, const float* __restrict__ bo, float* __restrict__ rstdy)
{
  int row = blockIdx.x * 4 + (threadIdx.x >> 6);      // 0..8191
  int lane = threadIdx.x & 63;
  const float* yr = ytmp + (long)row * C_N;
  float s = 0.f;
#pragma unroll
  for (int j = 0; j < 2; ++j) {
    float4 v = ((const float4*)yr)[lane * 2 + j];
    float4 bb = ((const float4*)bo)[lane * 2 + j];
    v.x += bb.x; v.y += bb.y; v.z += bb.z; v.w += bb.w;
    s += v.x*v.x + v.y*v.y + v.z*v.z + v.w*v.w;
  }
#pragma unroll
  for (int m = 1; m < 64; m <<= 1) s += __shfl_xor(s, m);
  rstdy[row] = rsqrtf(s * (1.0f / C_N) + EPSN);
}

// ---------------- K8: final transpose + bias + norm + residual ----------------
__global__ __launch_bounds__(256) void final_kernel(
    const float* __restrict__ ytmp, const float* __restrict__ bo,
    const float* __restrict__ g2, const float* __restrict__ rstdy,
    const float* __restrict__ x, float* __restrict__ out)
{
  __shared__ float tile[32][33];
  int b = blockIdx.z, c0 = blockIdx.y * 32, p0 = blockIdx.x * 32;
  int tx = threadIdx.x & 31, ty = threadIdx.x >> 5;
#pragma unroll
  for (int j = 0; j < 4; ++j) {
    int p = ty + j * 8;
    tile[p][tx] = ytmp[((long)b * HW_N + p0 + p) * C_N + c0 + tx] + bo[c0 + tx];
  }
  __syncthreads();
#pragma unroll
  for (int j = 0; j < 4; ++j) {
    int c = ty + j * 8;
    long oidx = ((long)b * C_N + c0 + c) * HW_N + p0 + tx;
    out[oidx] = tile[tx][c] * rstdy[b * HW_N + p0 + tx] * g2[c0 + c] + x[oidx];
  }
}

// ---------------- launch ----------------
extern "C" void kernel_launch(void* const* d_in, const int* in_sizes, int n_in,
                              void* d_out, int out_size, void* d_ws, size_t ws_size,
                              hipStream_t stream) {
  const float* x   = (const float*)d_in[0];
  const float* ctx = (const float*)d_in[1];
  const float* Wq  = (const float*)d_in[2];
  const float* Wkv = (const float*)d_in[3];
  const float* Wo  = (const float*)d_in[4];
  const float* bo  = (const float*)d_in[5];
  const float* g   = (const float*)d_in[6];
  const float* g2  = (const float*)d_in[7];
  float* out = (float*)d_out;

  char* ws = (char*)d_ws;
  bf16*  Wqg   = (bf16*)(ws + 0);          //  512*512*2  = 524288
  bf16*  Wkvg  = (bf16*)(ws + 524288);     // 1024*512*2  = 1048576
  bf16*  Wob   = (bf16*)(ws + 1572864);    //  512*512*2  = 524288
  float* rstdx = (float*)(ws + 2097152);   // 8192*4      = 32768
  float* rstdy = (float*)(ws + 2129920);   // 8192*4      = 32768
  bf16*  xbf   = (bf16*)(ws + 2162688);    // 8*1024*512*2 = 8388608
  bf16*  cnbf  = (bf16*)(ws + 10551296);   // 8388608
  bf16*  qbf   = (bf16*)(ws + 18939904);   // 8388608
  bf16*  kvbf  = (bf16*)(ws + 27328512);   // 8*1024*1024*2 = 16777216
  bf16*  vT    = (bf16*)(ws + 44105728);   // 8388608
  bf16*  attno = (bf16*)(ws + 52494336);   // 8388608
  float* ytmp  = (float*)(ws + 2162688);   // aliases xbf+cnbf (dead by then)

  prep_weights<<<4096, 256, 0, stream>>>(Wq, Wkv, Wo, g, Wqg, Wkvg, Wob);
  rstd_ch_kernel<<<128, 256, 0, stream>>>(x, rstdx);
  xbf_kernel<<<dim3(32, 16, 8), 256, 0, stream>>>(x, rstdx, xbf);
  ctxnorm_kernel<<<2048, 256, 0, stream>>>(ctx, cnbf);

  gemm_nt<0><<<dim3(4, 8, 8), 256, 0, stream>>>(
      xbf, Wqg, qbf, nullptr, HW_N, HID_N, C_N, 0.125f,
      (long)HW_N * C_N, (long)HW_N * HID_N);
  gemm_nt<1><<<dim3(8, 8, 8), 256, 0, stream>>>(
      cnbf, Wkvg, kvbf, vT, LC_N, 2 * HID_N, C_N, 1.0f,
      (long)LC_N * C_N, (long)LC_N * 2 * HID_N);

  attn_fused<<<dim3(8, 64), 256, 0, stream>>>(qbf, kvbf, vT, attno);

  gemm_nt<2><<<dim3(4, 8, 8), 256, 0, stream>>>(
      attno, Wob, ytmp, nullptr, HW_N, C_N, HID_N, 1.0f,
      (long)HW_N * HID_N, (long)HW_N * C_N);

  ystats_kernel<<<2048, 256, 0, stream>>>(ytmp, bo, rstdy);
  final_kernel<<<dim3(32, 16, 8), 256, 0, stream>>>(ytmp, bo, g2, rstdy, x, out);
}

// Round 3
// 238.630 us; speedup vs baseline: 1.2581x; 1.0213x over previous
//
#include <hip/hip_runtime.h>
#include <hip/hip_bf16.h>

using bf16 = __hip_bfloat16;
typedef float f32x4 __attribute__((ext_vector_type(4)));
typedef short s16x8 __attribute__((ext_vector_type(8)));
typedef short s16x4 __attribute__((ext_vector_type(4)));

#define B_N   8
#define C_N   512
#define HW_N  1024
#define LC_N  1024
#define HID_N 512
#define NHEAD 8
#define DHEAD 64
#define EPSN  1e-6f

__device__ __forceinline__ f32x4 mfma16(s16x8 a, s16x8 b, f32x4 c) {
  return __builtin_amdgcn_mfma_f32_16x16x32_bf16(a, b, c, 0, 0, 0);
}
__device__ __forceinline__ void gload_lds16(const void* g, void* l) {
  __builtin_amdgcn_global_load_lds((const __attribute__((address_space(1))) void*)g,
                                   (__attribute__((address_space(3))) void*)l, 16, 0, 0);
}
__device__ __forceinline__ s16x8 ld8(const bf16* p) {
  return *reinterpret_cast<const s16x8*>(p);
}
__device__ __forceinline__ unsigned short bfbits(float f) {
  return __builtin_bit_cast(unsigned short, __float2bfloat16(f));
}

// ---------------- K0: weight prep (fold g, convert to bf16) ----------------
__global__ __launch_bounds__(256) void prep_weights(
    const float* __restrict__ Wq, const float* __restrict__ Wkv,
    const float* __restrict__ Wo, const float* __restrict__ g,
    bf16* __restrict__ Wqg, bf16* __restrict__ Wkvg, bf16* __restrict__ Wob)
{
  int idx = blockIdx.x * 256 + threadIdx.x;           // 0 .. 1048575
  const int NQ = 512 * 512, NKV = 1024 * 512;
  if (idx < NQ) {
    Wqg[idx] = __float2bfloat16(Wq[idx] * g[idx & 511]);
  } else if (idx < NQ + NKV) {
    int j = idx - NQ;
    Wkvg[j] = __float2bfloat16(Wkv[j] * g[j & 511]);
  } else {
    int j = idx - NQ - NKV;
    Wob[j] = __float2bfloat16(Wo[j]);
  }
}

// ---------------- K1: per-pixel rstd of x over channels ----------------
__global__ __launch_bounds__(256) void rstd_ch_kernel(
    const float* __restrict__ x, float* __restrict__ rstd)
{
  __shared__ float part[4][64];
  int tp = threadIdx.x & 63, tc = threadIdx.x >> 6;
  int gp = blockIdx.x * 64 + tp;                      // 0..8191
  int b = gp >> 10, p = gp & 1023;
  const float* xb = x + (long)b * C_N * HW_N + p;
  float s = 0.f;
  for (int c = tc * 128; c < tc * 128 + 128; ++c) {
    float v = xb[(long)c * HW_N];
    s += v * v;
  }
  part[tc][tp] = s;
  __syncthreads();
  if (tc == 0) {
    float tot = part[0][tp] + part[1][tp] + part[2][tp] + part[3][tp];
    rstd[gp] = rsqrtf(tot * (1.0f / C_N) + EPSN);
  }
}

// ---------------- K2: xbf[b][p][c] = bf16(x[b][c][p] * rstd) (transpose) ----------------
__global__ __launch_bounds__(256) void xbf_kernel(
    const float* __restrict__ x, const float* __restrict__ rstd, bf16* __restrict__ xbf)
{
  __shared__ float tile[32][33];
  int b = blockIdx.z, c0 = blockIdx.y * 32, p0 = blockIdx.x * 32;
  int tx = threadIdx.x & 31, ty = threadIdx.x >> 5;   // ty 0..7
#pragma unroll
  for (int j = 0; j < 4; ++j) {
    int c = ty + j * 8;
    tile[c][tx] = x[((long)b * C_N + c0 + c) * HW_N + p0 + tx];
  }
  __syncthreads();
#pragma unroll
  for (int j = 0; j < 4; ++j) {
    int p = ty + j * 8;
    float r = rstd[b * HW_N + p0 + p];
    xbf[((long)b * HW_N + p0 + p) * C_N + c0 + tx] = __float2bfloat16(tile[tx][p] * r);
  }
}

// ---------------- K3: context RMSNorm -> bf16 (rows contiguous) ----------------
__global__ __launch_bounds__(256) void ctxnorm_kernel(
    const float* __restrict__ ctx, bf16* __restrict__ cnbf)
{
  int row = blockIdx.x * 4 + (threadIdx.x >> 6);      // 0..8191
  int lane = threadIdx.x & 63;
  const float* cr = ctx + (long)row * C_N;
  float4 v0 = ((const float4*)cr)[lane * 2];
  float4 v1 = ((const float4*)cr)[lane * 2 + 1];
  float s = v0.x*v0.x + v0.y*v0.y + v0.z*v0.z + v0.w*v0.w
          + v1.x*v1.x + v1.y*v1.y + v1.z*v1.z + v1.w*v1.w;
#pragma unroll
  for (int m = 1; m < 64; m <<= 1) s += __shfl_xor(s, m);
  float r = rsqrtf(s * (1.0f / C_N) + EPSN);
  bf16 tmp[8];
  tmp[0] = __float2bfloat16(v0.x * r); tmp[1] = __float2bfloat16(v0.y * r);
  tmp[2] = __float2bfloat16(v0.z * r); tmp[3] = __float2bfloat16(v0.w * r);
  tmp[4] = __float2bfloat16(v1.x * r); tmp[5] = __float2bfloat16(v1.y * r);
  tmp[6] = __float2bfloat16(v1.z * r); tmp[7] = __float2bfloat16(v1.w * r);
  *reinterpret_cast<s16x8*>(cnbf + (long)row * C_N + lane * 8) =
      *reinterpret_cast<const s16x8*>(tmp);
}

// ---------------- K4: NT MFMA GEMM, 2-phase double-buffered (T3-min) ----------------
// C[M,N] = A[M,K] * B[N,K]^T
// MODE 0: bf16 out with scale (Q).  MODE 1: bf16 out + vT copy (KV).  MODE 2: fp32 out.
template<int MODE>
__global__ __launch_bounds__(256)
void gemm_nt(const bf16* __restrict__ A, const bf16* __restrict__ W,
             void* __restrict__ outp, bf16* __restrict__ vT,
             int M, int N, int K, float scale, long strideA, long strideOut)
{
  __shared__ bf16 sA[2][128 * 32];
  __shared__ bf16 sB[2][128 * 32];
  const int t = threadIdx.x;
  const int b = blockIdx.z;
  const int m0 = blockIdx.y * 128;
  const int n0 = blockIdx.x * 128;
  const bf16* Ab = A + (long)b * strideA;
  const int lane = t & 63;
  const int w = t >> 6;
  const int wm = (w >> 1) * 64, wn = (w & 1) * 64;
  const int lr = lane & 15, hi = lane >> 4;
  const int r = t >> 2, seg = t & 3;

  const long aoff0 = (long)(m0 + r) * K + seg * 8;
  const long aoff1 = (long)(m0 + 64 + r) * K + seg * 8;
  const long woff0 = (long)(n0 + r) * K + seg * 8;
  const long woff1 = (long)(n0 + 64 + r) * K + seg * 8;
  const int ldst0 = r * 32 + seg * 8, ldst1 = (64 + r) * 32 + seg * 8;

  f32x4 acc[4][4] = {};

#define STAGE(buf, k0)                                       \
  do {                                                       \
    gload_lds16(Ab + aoff0 + (k0), &sA[buf][ldst0]);         \
    gload_lds16(Ab + aoff1 + (k0), &sA[buf][ldst1]);         \
    gload_lds16(W  + woff0 + (k0), &sB[buf][ldst0]);         \
    gload_lds16(W  + woff1 + (k0), &sB[buf][ldst1]);         \
  } while (0)

  STAGE(0, 0);
  __syncthreads();                      // compiler inserts vmcnt(0) before barrier
  int cur = 0;
  for (int k0 = 0; k0 < K; k0 += 32) {
    if (k0 + 32 < K) STAGE(cur ^ 1, k0 + 32);   // loads fly during compute
    s16x8 af[4], bfr[4];
#pragma unroll
    for (int mi = 0; mi < 4; ++mi)
      af[mi] = *reinterpret_cast<const s16x8*>(&sA[cur][(wm + mi * 16 + lr) * 32 + hi * 8]);
#pragma unroll
    for (int ni = 0; ni < 4; ++ni)
      bfr[ni] = *reinterpret_cast<const s16x8*>(&sB[cur][(wn + ni * 16 + lr) * 32 + hi * 8]);
#pragma unroll
    for (int mi = 0; mi < 4; ++mi)
#pragma unroll
      for (int ni = 0; ni < 4; ++ni)
        acc[mi][ni] = mfma16(af[mi], bfr[ni], acc[mi][ni]);
    __syncthreads();                    // drains next tile's loads exactly once
    cur ^= 1;
  }
#undef STAGE

#pragma unroll
  for (int mi = 0; mi < 4; ++mi) {
#pragma unroll
    for (int ni = 0; ni < 4; ++ni) {
#pragma unroll
      for (int rr = 0; rr < 4; ++rr) {
        int row = m0 + wm + mi * 16 + hi * 4 + rr;
        int col = n0 + wn + ni * 16 + lr;
        float v = acc[mi][ni][rr] * scale;
        if (MODE == 2) {
          ((float*)outp)[(long)b * strideOut + (long)row * N + col] = v;
        } else {
          ((bf16*)outp)[(long)b * strideOut + (long)row * N + col] = __float2bfloat16(v);
          if (MODE == 1 && col >= HID_N) {
            vT[((long)b * HID_N + (col - HID_N)) * LC_N + row] = __float2bfloat16(v);
          }
        }
      }
    }
  }
}

// ---------------- K5: fused flash attention (1 wave = 32 query rows, 64-key blocks) ----
// Grid: x = bh (XCD-grouping: all q-blocks of one (b,h) share an XCD L2), y = q-block.
// Swapped QK^T; exp2-domain softmax (log2e folded into Q scale); defer-max THR=8;
// register-prefetched K/V.
__global__ __launch_bounds__(256)
void attn_fused(const bf16* __restrict__ qbf, const bf16* __restrict__ kvbf,
                const bf16* __restrict__ vT, bf16* __restrict__ attno)
{
  __shared__ bf16 Pl[4][32 * 72];                     // per-wave P tile, stride 72 (pad)
  const int t = threadIdx.x;
  const int wv = t >> 6, lane = t & 63;
  const int lr = lane & 15, hi = lane >> 4;
  const int hi8 = hi * 8, hi4 = hi * 4;
  const int bh = blockIdx.x, b = bh >> 3, h = bh & 7;
  const int q_base = blockIdx.y * 128 + wv * 32;

  s16x8 qf[2][2];
#pragma unroll
  for (int qt = 0; qt < 2; ++qt)
#pragma unroll
    for (int c = 0; c < 2; ++c)
      qf[qt][c] = ld8(qbf + ((long)b * HW_N + q_base + qt * 16 + lr) * HID_N
                          + h * DHEAD + c * 32 + hi8);

  const bf16* kbase = kvbf + (long)b * LC_N * 1024 + h * DHEAD;        // row stride 1024
  const bf16* vbase = vT + ((long)b * HID_N + h * DHEAD) * (long)LC_N; // [d][l]
  bf16* Pw = Pl[wv];

  float m[2] = {-1e30f, -1e30f};
  float lsum[2] = {0.f, 0.f};
  f32x4 o[2][4] = {};

  s16x8 kf[4][2];
  s16x8 vf[4][2];

#pragma unroll
  for (int kt = 0; kt < 4; ++kt)
#pragma unroll
    for (int c = 0; c < 2; ++c)
      kf[kt][c] = ld8(kbase + (long)(kt * 16 + lr) * 1024 + c * 32 + hi8);

#pragma unroll 1
  for (int l0 = 0; l0 < LC_N; l0 += 64) {
#pragma unroll
    for (int dt = 0; dt < 4; ++dt)
#pragma unroll
      for (int c = 0; c < 2; ++c)
        vf[dt][c] = ld8(vbase + (long)(dt * 16 + lr) * LC_N + l0 + c * 32 + hi8);

    // QK^T (swapped operands) — scores already in log2 domain
    f32x4 st[4][2] = {};
#pragma unroll
    for (int kt = 0; kt < 4; ++kt)
#pragma unroll
      for (int qt = 0; qt < 2; ++qt) {
        st[kt][qt] = mfma16(kf[kt][0], qf[qt][0], st[kt][qt]);
        st[kt][qt] = mfma16(kf[kt][1], qf[qt][1], st[kt][qt]);
      }

    if (l0 + 64 < LC_N) {
#pragma unroll
      for (int kt = 0; kt < 4; ++kt)
#pragma unroll
        for (int c = 0; c < 2; ++c)
          kf[kt][c] = ld8(kbase + (long)(l0 + 64 + kt * 16 + lr) * 1024 + c * 32 + hi8);
    }

    float pmax[2];
#pragma unroll
    for (int qt = 0; qt < 2; ++qt) {
      float mx = st[0][qt][0];
#pragma unroll
      for (int kt = 0; kt < 4; ++kt)
#pragma unroll
        for (int rr = 0; rr < 4; ++rr)
          mx = fmaxf(mx, st[kt][qt][rr]);
      pmax[qt] = mx;
    }
    bool ok = (pmax[0] <= m[0] + 8.f) && (pmax[1] <= m[1] + 8.f);
    if (!__all(ok)) {
#pragma unroll
      for (int qt = 0; qt < 2; ++qt) {
        float rm = pmax[qt];
        rm = fmaxf(rm, __shfl_xor(rm, 16));
        rm = fmaxf(rm, __shfl_xor(rm, 32));
        float mn = fmaxf(m[qt], rm);
        float al = __builtin_amdgcn_exp2f(m[qt] - mn);
        m[qt] = mn;
        lsum[qt] *= al;
        float arr[4];
#pragma unroll
        for (int rr = 0; rr < 4; ++rr) arr[rr] = __shfl(al, hi4 + rr);
#pragma unroll
        for (int dt = 0; dt < 4; ++dt)
#pragma unroll
          for (int rr = 0; rr < 4; ++rr) o[qt][dt][rr] *= arr[rr];
      }
    }

    // P = exp2(s - m), pack bf16 -> per-wave LDS; per-lane lsum partials
#pragma unroll
    for (int qt = 0; qt < 2; ++qt) {
      float ls = 0.f;
#pragma unroll
      for (int kt = 0; kt < 4; ++kt) {
        float p0 = __builtin_amdgcn_exp2f(st[kt][qt][0] - m[qt]);
        float p1 = __builtin_amdgcn_exp2f(st[kt][qt][1] - m[qt]);
        float p2 = __builtin_amdgcn_exp2f(st[kt][qt][2] - m[qt]);
        float p3 = __builtin_amdgcn_exp2f(st[kt][qt][3] - m[qt]);
        ls += (p0 + p1) + (p2 + p3);
        s16x4 pk;
        pk[0] = (short)bfbits(p0); pk[1] = (short)bfbits(p1);
        pk[2] = (short)bfbits(p2); pk[3] = (short)bfbits(p3);
        *reinterpret_cast<s16x4*>(&Pw[(qt * 16 + lr) * 72 + kt * 16 + hi4]) = pk;
      }
      lsum[qt] += ls;
    }

#pragma unroll
    for (int qt = 0; qt < 2; ++qt) {
#pragma unroll
      for (int c = 0; c < 2; ++c) {
        s16x8 pa = *reinterpret_cast<const s16x8*>(&Pw[(qt * 16 + lr) * 72 + c * 32 + hi8]);
#pragma unroll
        for (int dt = 0; dt < 4; ++dt)
          o[qt][dt] = mfma16(pa, vf[dt][c], o[qt][dt]);
      }
    }
  }

#pragma unroll
  for (int qt = 0; qt < 2; ++qt) {
    float ls = lsum[qt];
    ls += __shfl_xor(ls, 16);
    ls += __shfl_xor(ls, 32);
    float linv[4];
#pragma unroll
    for (int rr = 0; rr < 4; ++rr) linv[rr] = 1.f / __shfl(ls, hi4 + rr);
#pragma unroll
    for (int dt = 0; dt < 4; ++dt)
#pragma unroll
      for (int rr = 0; rr < 4; ++rr)
        attno[((long)b * HW_N + q_base + qt * 16 + hi4 + rr) * HID_N
              + h * DHEAD + dt * 16 + lr] = __float2bfloat16(o[qt][dt][rr] * linv[rr]);
  }
}

// ---------------- K7: y row stats (with bias) ----------------
__global__ __launch_bounds__(256) void ystats_kernel(
    const float* __restrict__ ytmp, const float* __restrict__ bo, float* __restrict__ rstdy)
{
  int row = blockIdx.x * 4 + (threadIdx.x >> 6);      // 0..8191
  int lane = threadIdx.x & 63;
  const float* yr = ytmp + (long)row * C_N;
  float s = 0.f;
#pragma unroll
  for (int j = 0; j < 2; ++j) {
    float4 v = ((const float4*)yr)[lane * 2 + j];
    float4 bb = ((const float4*)bo)[lane * 2 + j];
    v.x += bb.x; v.y += bb.y; v.z += bb.z; v.w += bb.w;
    s += v.x*v.x + v.y*v.y + v.z*v.z + v.w*v.w;
  }
#pragma unroll
  for (int m = 1; m < 64; m <<= 1) s += __shfl_xor(s, m);
  rstdy[row] = rsqrtf(s * (1.0f / C_N) + EPSN);
}

// ---------------- K8: final transpose + bias + norm + residual ----------------
__global__ __launch_bounds__(256) void final_kernel(
    const float* __restrict__ ytmp, const float* __restrict__ bo,
    const float* __restrict__ g2, const float* __restrict__ rstdy,
    const float* __restrict__ x, float* __restrict__ out)
{
  __shared__ float tile[32][33];
  int b = blockIdx.z, c0 = blockIdx.y * 32, p0 = blockIdx.x * 32;
  int tx = threadIdx.x & 31, ty = threadIdx.x >> 5;
#pragma unroll
  for (int j = 0; j < 4; ++j) {
    int p = ty + j * 8;
    tile[p][tx] = ytmp[((long)b * HW_N + p0 + p) * C_N + c0 + tx] + bo[c0 + tx];
  }
  __syncthreads();
#pragma unroll
  for (int j = 0; j < 4; ++j) {
    int c = ty + j * 8;
    long oidx = ((long)b * C_N + c0 + c) * HW_N + p0 + tx;
    out[oidx] = tile[tx][c] * rstdy[b * HW_N + p0 + tx] * g2[c0 + c] + x[oidx];
  }
}

// ---------------- launch ----------------
extern "C" void kernel_launch(void* const* d_in, const int* in_sizes, int n_in,
                              void* d_out, int out_size, void* d_ws, size_t ws_size,
                              hipStream_t stream) {
  const float* x   = (const float*)d_in[0];
  const float* ctx = (const float*)d_in[1];
  const float* Wq  = (const float*)d_in[2];
  const float* Wkv = (const float*)d_in[3];
  const float* Wo  = (const float*)d_in[4];
  const float* bo  = (const float*)d_in[5];
  const float* g   = (const float*)d_in[6];
  const float* g2  = (const float*)d_in[7];
  float* out = (float*)d_out;

  char* ws = (char*)d_ws;
  bf16*  Wqg   = (bf16*)(ws + 0);          //  512*512*2  = 524288
  bf16*  Wkvg  = (bf16*)(ws + 524288);     // 1024*512*2  = 1048576
  bf16*  Wob   = (bf16*)(ws + 1572864);    //  512*512*2  = 524288
  float* rstdx = (float*)(ws + 2097152);   // 8192*4      = 32768
  float* rstdy = (float*)(ws + 2129920);   // 8192*4      = 32768
  bf16*  xbf   = (bf16*)(ws + 2162688);    // 8*1024*512*2 = 8388608
  bf16*  cnbf  = (bf16*)(ws + 10551296);   // 8388608
  bf16*  qbf   = (bf16*)(ws + 18939904);   // 8388608
  bf16*  kvbf  = (bf16*)(ws + 27328512);   // 8*1024*1024*2 = 16777216
  bf16*  vT    = (bf16*)(ws + 44105728);   // 8388608
  bf16*  attno = (bf16*)(ws + 52494336);   // 8388608
  float* ytmp  = (float*)(ws + 2162688);   // aliases xbf+cnbf (dead by then)

  prep_weights<<<4096, 256, 0, stream>>>(Wq, Wkv, Wo, g, Wqg, Wkvg, Wob);
  rstd_ch_kernel<<<128, 256, 0, stream>>>(x, rstdx);
  xbf_kernel<<<dim3(32, 16, 8), 256, 0, stream>>>(x, rstdx, xbf);
  ctxnorm_kernel<<<2048, 256, 0, stream>>>(ctx, cnbf);

  // Q scale folds softmax's log2(e): 0.125 * 1.4426950408889634
  gemm_nt<0><<<dim3(4, 8, 8), 256, 0, stream>>>(
      xbf, Wqg, qbf, nullptr, HW_N, HID_N, C_N, 0.18033688011112042f,
      (long)HW_N * C_N, (long)HW_N * HID_N);
  gemm_nt<1><<<dim3(8, 8, 8), 256, 0, stream>>>(
      cnbf, Wkvg, kvbf, vT, LC_N, 2 * HID_N, C_N, 1.0f,
      (long)LC_N * C_N, (long)LC_N * 2 * HID_N);

  attn_fused<<<dim3(64, 8), 256, 0, stream>>>(qbf, kvbf, vT, attno);

  gemm_nt<2><<<dim3(4, 8, 8), 256, 0, stream>>>(
      attno, Wob, ytmp, nullptr, HW_N, C_N, HID_N, 1.0f,
      (long)HW_N * HID_N, (long)HW_N * C_N);

  ystats_kernel<<<2048, 256, 0, stream>>>(ytmp, bo, rstdy);
  final_kernel<<<dim3(32, 16, 8), 256, 0, stream>>>(ytmp, bo, g2, rstdy, x, out);
}

// Round 4
// 192.580 us; speedup vs baseline: 1.5590x; 1.2391x over previous
//
#include <hip/hip_runtime.h>
#include <hip/hip_bf16.h>

using bf16 = __hip_bfloat16;
typedef float f32x4 __attribute__((ext_vector_type(4)));
typedef short s16x8 __attribute__((ext_vector_type(8)));
typedef short s16x4 __attribute__((ext_vector_type(4)));

#define B_N   8
#define C_N   512
#define HW_N  1024
#define LC_N  1024
#define HID_N 512
#define NHEAD 8
#define DHEAD 64
#define EPSN  1e-6f

__device__ __forceinline__ f32x4 mfma16(s16x8 a, s16x8 b, f32x4 c) {
  return __builtin_amdgcn_mfma_f32_16x16x32_bf16(a, b, c, 0, 0, 0);
}
__device__ __forceinline__ void gload_lds16(const void* g, void* l) {
  __builtin_amdgcn_global_load_lds((const __attribute__((address_space(1))) void*)g,
                                   (__attribute__((address_space(3))) void*)l, 16, 0, 0);
}
__device__ __forceinline__ s16x8 ld8(const bf16* p) {
  return *reinterpret_cast<const s16x8*>(p);
}
__device__ __forceinline__ unsigned short bfbits(float f) {
  return __builtin_bit_cast(unsigned short, __float2bfloat16(f));
}

// ---------------- K0: weight prep (fold g, convert to bf16) ----------------
__global__ __launch_bounds__(256) void prep_weights(
    const float* __restrict__ Wq, const float* __restrict__ Wkv,
    const float* __restrict__ Wo, const float* __restrict__ g,
    bf16* __restrict__ Wqg, bf16* __restrict__ Wkvg, bf16* __restrict__ Wob)
{
  int idx = blockIdx.x * 256 + threadIdx.x;           // 0 .. 1048575
  const int NQ = 512 * 512, NKV = 1024 * 512;
  if (idx < NQ) {
    Wqg[idx] = __float2bfloat16(Wq[idx] * g[idx & 511]);
  } else if (idx < NQ + NKV) {
    int j = idx - NQ;
    Wkvg[j] = __float2bfloat16(Wkv[j] * g[j & 511]);
  } else {
    int j = idx - NQ - NKV;
    Wob[j] = __float2bfloat16(Wo[j]);
  }
}

// ---------------- K1: per-pixel rstd of x over channels ----------------
__global__ __launch_bounds__(256) void rstd_ch_kernel(
    const float* __restrict__ x, float* __restrict__ rstd)
{
  __shared__ float part[4][64];
  int tp = threadIdx.x & 63, tc = threadIdx.x >> 6;
  int gp = blockIdx.x * 64 + tp;                      // 0..8191
  int b = gp >> 10, p = gp & 1023;
  const float* xb = x + (long)b * C_N * HW_N + p;
  float s = 0.f;
  for (int c = tc * 128; c < tc * 128 + 128; ++c) {
    float v = xb[(long)c * HW_N];
    s += v * v;
  }
  part[tc][tp] = s;
  __syncthreads();
  if (tc == 0) {
    float tot = part[0][tp] + part[1][tp] + part[2][tp] + part[3][tp];
    rstd[gp] = rsqrtf(tot * (1.0f / C_N) + EPSN);
  }
}

// ---------------- K2: xbf[b][p][c] = bf16(x[b][c][p] * rstd) (transpose) ----------------
__global__ __launch_bounds__(256) void xbf_kernel(
    const float* __restrict__ x, const float* __restrict__ rstd, bf16* __restrict__ xbf)
{
  __shared__ float tile[32][33];
  int b = blockIdx.z, c0 = blockIdx.y * 32, p0 = blockIdx.x * 32;
  int tx = threadIdx.x & 31, ty = threadIdx.x >> 5;   // ty 0..7
#pragma unroll
  for (int j = 0; j < 4; ++j) {
    int c = ty + j * 8;
    tile[c][tx] = x[((long)b * C_N + c0 + c) * HW_N + p0 + tx];
  }
  __syncthreads();
#pragma unroll
  for (int j = 0; j < 4; ++j) {
    int p = ty + j * 8;
    float r = rstd[b * HW_N + p0 + p];
    xbf[((long)b * HW_N + p0 + p) * C_N + c0 + tx] = __float2bfloat16(tile[tx][p] * r);
  }
}

// ---------------- K3: context RMSNorm -> bf16 (rows contiguous) ----------------
__global__ __launch_bounds__(256) void ctxnorm_kernel(
    const float* __restrict__ ctx, bf16* __restrict__ cnbf)
{
  int row = blockIdx.x * 4 + (threadIdx.x >> 6);      // 0..8191
  int lane = threadIdx.x & 63;
  const float* cr = ctx + (long)row * C_N;
  float4 v0 = ((const float4*)cr)[lane * 2];
  float4 v1 = ((const float4*)cr)[lane * 2 + 1];
  float s = v0.x*v0.x + v0.y*v0.y + v0.z*v0.z + v0.w*v0.w
          + v1.x*v1.x + v1.y*v1.y + v1.z*v1.z + v1.w*v1.w;
#pragma unroll
  for (int m = 1; m < 64; m <<= 1) s += __shfl_xor(s, m);
  float r = rsqrtf(s * (1.0f / C_N) + EPSN);
  bf16 tmp[8];
  tmp[0] = __float2bfloat16(v0.x * r); tmp[1] = __float2bfloat16(v0.y * r);
  tmp[2] = __float2bfloat16(v0.z * r); tmp[3] = __float2bfloat16(v0.w * r);
  tmp[4] = __float2bfloat16(v1.x * r); tmp[5] = __float2bfloat16(v1.y * r);
  tmp[6] = __float2bfloat16(v1.z * r); tmp[7] = __float2bfloat16(v1.w * r);
  *reinterpret_cast<s16x8*>(cnbf + (long)row * C_N + lane * 8) =
      *reinterpret_cast<const s16x8*>(tmp);
}

// ---------------- K4: NT MFMA GEMM, 128x64 tile, 2-phase dbuf ----------------
// C[8192,N] = A[8192,K] * W[N,K]^T. Batch folded into rows (row = b*1024 + p).
// MODE 0: bf16 out + scale. MODE 1: bf16 K-half out + vT scatter of V-half. MODE 2: fp32.
template<int MODE>
__global__ __launch_bounds__(256, 4)
void gemm_nt(const bf16* __restrict__ A, const bf16* __restrict__ W,
             void* __restrict__ outp, bf16* __restrict__ vT,
             int N, int K, float scale)
{
  __shared__ bf16 sA[2][128 * 32];
  __shared__ bf16 sB[2][64 * 32];
  const int t = threadIdx.x;
  const int m0 = blockIdx.x * 128;                  // x = M tiles -> same XCD shares A
  const int n0 = blockIdx.y * 64;
  const int lane = t & 63;
  const int w = t >> 6;
  const int wm = w * 32;                            // wave tile 32Mx64N
  const int lr = lane & 15, hi = lane >> 4;
  const int r = t >> 2, seg = t & 3;

  const long aoff0 = (long)(m0 + r) * K + seg * 8;
  const long aoff1 = (long)(m0 + 64 + r) * K + seg * 8;
  const long woff  = (long)(n0 + r) * K + seg * 8;
  const int ld8i = t * 8;                           // == wave-linear 16B slots

  f32x4 acc[2][4] = {};

#define GSTAGE(buf, k0)                                    \
  do {                                                     \
    gload_lds16(A + aoff0 + (k0), &sA[buf][ld8i]);         \
    gload_lds16(A + aoff1 + (k0), &sA[buf][2048 + ld8i]);  \
    gload_lds16(W + woff  + (k0), &sB[buf][ld8i]);         \
  } while (0)

  GSTAGE(0, 0);
  __syncthreads();
  int cur = 0;
  for (int k0 = 0; k0 < K; k0 += 32) {
    if (k0 + 32 < K) GSTAGE(cur ^ 1, k0 + 32);      // next tile flies during compute
    s16x8 af[2], bfr[4];
#pragma unroll
    for (int mi = 0; mi < 2; ++mi)
      af[mi] = *reinterpret_cast<const s16x8*>(&sA[cur][(wm + mi * 16 + lr) * 32 + hi * 8]);
#pragma unroll
    for (int ni = 0; ni < 4; ++ni)
      bfr[ni] = *reinterpret_cast<const s16x8*>(&sB[cur][(ni * 16 + lr) * 32 + hi * 8]);
#pragma unroll
    for (int mi = 0; mi < 2; ++mi)
#pragma unroll
      for (int ni = 0; ni < 4; ++ni)
        acc[mi][ni] = mfma16(af[mi], bfr[ni], acc[mi][ni]);
    __syncthreads();
    cur ^= 1;
  }
#undef GSTAGE

#pragma unroll
  for (int mi = 0; mi < 2; ++mi) {
#pragma unroll
    for (int ni = 0; ni < 4; ++ni) {
#pragma unroll
      for (int rr = 0; rr < 4; ++rr) {
        int row = m0 + wm + mi * 16 + hi * 4 + rr;
        int col = n0 + ni * 16 + lr;
        float v = acc[mi][ni][rr] * scale;
        if (MODE == 2) {
          ((float*)outp)[(long)row * N + col] = v;
        } else if (MODE == 0) {
          ((bf16*)outp)[(long)row * N + col] = __float2bfloat16(v);
        } else {                                    // MODE 1
          if (col < HID_N) {
            ((bf16*)outp)[(long)row * N + col] = __float2bfloat16(v);
          } else {                                  // V half -> transposed only
            int b = row >> 10, l = row & 1023;
            vT[((long)b * HID_N + (col - HID_N)) * LC_N + l] = __float2bfloat16(v);
          }
        }
      }
    }
  }
}

// ---------------- K5: fused flash attention ----------------
// Block = 4 waves, 128 q-rows, one (b,h). K/V tiles (64 keys) staged cooperatively
// into LDS (2-phase dbuf, global_load_lds). Sub-tiled as two 64B half-rows so all
// ds_read_b128 are contiguous 1KB wave accesses (conflict-free, no swizzle).
// Swapped QK^T; exp2 softmax (log2e folded in Q); defer-max THR=8.
__global__ __launch_bounds__(256, 2)
void attn_fused(const bf16* __restrict__ qbf, const bf16* __restrict__ kvbf,
                const bf16* __restrict__ vT, bf16* __restrict__ attno)
{
  __shared__ bf16 sK[2][4096];                      // [buf][c*2048 + row*32 + e]
  __shared__ bf16 sV[2][4096];
  __shared__ bf16 Pl[4][32 * 72];                   // per-wave P, stride 72 (pad)
  const int t = threadIdx.x;
  const int wv = t >> 6, lane = t & 63;
  const int lr = lane & 15, hi = lane >> 4;
  const int hi8 = hi * 8, hi4 = hi * 4;
  const int bh = blockIdx.x, b = bh >> 3, h = bh & 7;
  const int q_base = blockIdx.y * 128 + wv * 32;

  const bf16* kbase = kvbf + (long)b * LC_N * 1024 + h * DHEAD;        // row stride 1024
  const bf16* vbase = vT + ((long)b * HID_N + h * DHEAD) * (long)LC_N; // [d][l], stride 1024
  bf16* Pw = Pl[wv];

  // Q fragments [qt][c]
  s16x8 qf[2][2];
#pragma unroll
  for (int qt = 0; qt < 2; ++qt)
#pragma unroll
    for (int c = 0; c < 2; ++c)
      qf[qt][c] = ld8(qbf + ((long)b * HW_N + q_base + qt * 16 + lr) * HID_N
                          + h * DHEAD + c * 32 + hi8);

  // staging geometry: wave wv issues 4 of the block's 16 gload_lds per tile
  const int srow = lane >> 2;                       // 0..15
  const int scol = (lane & 3) * 8;                  // elems within 64B half-row

#define ASTAGE(buf, l0n)                                                        \
  do {                                                                          \
    _Pragma("unroll")                                                           \
    for (int j = 0; j < 4; ++j) {                                               \
      int lin = wv * 4 + j;                                                     \
      int cc = (lin >> 2) & 1, qq = lin & 3;                                    \
      if (lin < 8) {                                                            \
        gload_lds16(kbase + (long)((l0n) + qq * 16 + srow) * 1024 + cc * 32 + scol, \
                    &sK[buf][cc * 2048 + qq * 512 + lane * 8]);                 \
      } else {                                                                  \
        gload_lds16(vbase + (long)(qq * 16 + srow) * 1024 + (l0n) + cc * 32 + scol, \
                    &sV[buf][cc * 2048 + qq * 512 + lane * 8]);                 \
      }                                                                         \
    }                                                                           \
  } while (0)

  float m[2] = {-1e30f, -1e30f};
  float lsum[2] = {0.f, 0.f};
  f32x4 o[2][4] = {};

  ASTAGE(0, 0);
  __syncthreads();
  int cur = 0;

#pragma unroll 1
  for (int l0 = 0; l0 < LC_N; l0 += 64) {
    if (l0 + 64 < LC_N) ASTAGE(cur ^ 1, l0 + 64);   // next K/V tile flies during compute

    // QK^T (swapped): lane holds S[key = kt*16+hi4+rr][q = lr], log2 domain
    f32x4 st[4][2] = {};
#pragma unroll
    for (int kt = 0; kt < 4; ++kt) {
      s16x8 k0 = *reinterpret_cast<const s16x8*>(&sK[cur][(kt * 16 + lr) * 32 + hi8]);
      s16x8 k1 = *reinterpret_cast<const s16x8*>(&sK[cur][2048 + (kt * 16 + lr) * 32 + hi8]);
      st[kt][0] = mfma16(k0, qf[0][0], st[kt][0]);
      st[kt][0] = mfma16(k1, qf[0][1], st[kt][0]);
      st[kt][1] = mfma16(k0, qf[1][0], st[kt][1]);
      st[kt][1] = mfma16(k1, qf[1][1], st[kt][1]);
    }

    float pmax[2];
#pragma unroll
    for (int qt = 0; qt < 2; ++qt) {
      float mx = st[0][qt][0];
#pragma unroll
      for (int kt = 0; kt < 4; ++kt)
#pragma unroll
        for (int rr = 0; rr < 4; ++rr)
          mx = fmaxf(mx, st[kt][qt][rr]);
      pmax[qt] = mx;
    }
    bool ok = (pmax[0] <= m[0] + 8.f) && (pmax[1] <= m[1] + 8.f);
    if (!__all(ok)) {
#pragma unroll
      for (int qt = 0; qt < 2; ++qt) {
        float rm = pmax[qt];
        rm = fmaxf(rm, __shfl_xor(rm, 16));
        rm = fmaxf(rm, __shfl_xor(rm, 32));
        float mn = fmaxf(m[qt], rm);
        float al = __builtin_amdgcn_exp2f(m[qt] - mn);
        m[qt] = mn;
        lsum[qt] *= al;
        float arr[4];
#pragma unroll
        for (int rr = 0; rr < 4; ++rr) arr[rr] = __shfl(al, hi4 + rr);
#pragma unroll
        for (int dt = 0; dt < 4; ++dt)
#pragma unroll
          for (int rr = 0; rr < 4; ++rr) o[qt][dt][rr] *= arr[rr];
      }
    }

    // P = exp2(s - m) -> bf16 -> per-wave LDS; per-lane lsum partials
#pragma unroll
    for (int qt = 0; qt < 2; ++qt) {
      float ls = 0.f;
#pragma unroll
      for (int kt = 0; kt < 4; ++kt) {
        float p0 = __builtin_amdgcn_exp2f(st[kt][qt][0] - m[qt]);
        float p1 = __builtin_amdgcn_exp2f(st[kt][qt][1] - m[qt]);
        float p2 = __builtin_amdgcn_exp2f(st[kt][qt][2] - m[qt]);
        float p3 = __builtin_amdgcn_exp2f(st[kt][qt][3] - m[qt]);
        ls += (p0 + p1) + (p2 + p3);
        s16x4 pk;
        pk[0] = (short)bfbits(p0); pk[1] = (short)bfbits(p1);
        pk[2] = (short)bfbits(p2); pk[3] = (short)bfbits(p3);
        *reinterpret_cast<s16x4*>(&Pw[(qt * 16 + lr) * 72 + kt * 16 + hi4]) = pk;
      }
      lsum[qt] += ls;
    }

    // PV: P A-frags from LDS, V B-frags from staged LDS tile
#pragma unroll
    for (int c = 0; c < 2; ++c) {
      s16x8 pa0 = *reinterpret_cast<const s16x8*>(&Pw[(0 * 16 + lr) * 72 + c * 32 + hi8]);
      s16x8 pa1 = *reinterpret_cast<const s16x8*>(&Pw[(1 * 16 + lr) * 72 + c * 32 + hi8]);
#pragma unroll
      for (int dt = 0; dt < 4; ++dt) {
        s16x8 vv = *reinterpret_cast<const s16x8*>(
            &sV[cur][c * 2048 + (dt * 16 + lr) * 32 + hi8]);
        o[0][dt] = mfma16(pa0, vv, o[0][dt]);
        o[1][dt] = mfma16(pa1, vv, o[1][dt]);
      }
    }

    __syncthreads();                                // drains staged loads + LDS reads
    cur ^= 1;
  }
#undef ASTAGE

#pragma unroll
  for (int qt = 0; qt < 2; ++qt) {
    float ls = lsum[qt];
    ls += __shfl_xor(ls, 16);
    ls += __shfl_xor(ls, 32);
    float linv[4];
#pragma unroll
    for (int rr = 0; rr < 4; ++rr) linv[rr] = 1.f / __shfl(ls, hi4 + rr);
#pragma unroll
    for (int dt = 0; dt < 4; ++dt)
#pragma unroll
      for (int rr = 0; rr < 4; ++rr)
        attno[((long)b * HW_N + q_base + qt * 16 + hi4 + rr) * HID_N
              + h * DHEAD + dt * 16 + lr] = __float2bfloat16(o[qt][dt][rr] * linv[rr]);
  }
}

// ---------------- K7: y row stats (with bias) ----------------
__global__ __launch_bounds__(256) void ystats_kernel(
    const float* __restrict__ ytmp, const float* __restrict__ bo, float* __restrict__ rstdy)
{
  int row = blockIdx.x * 4 + (threadIdx.x >> 6);      // 0..8191
  int lane = threadIdx.x & 63;
  const float* yr = ytmp + (long)row * C_N;
  float s = 0.f;
#pragma unroll
  for (int j = 0; j < 2; ++j) {
    float4 v = ((const float4*)yr)[lane * 2 + j];
    float4 bb = ((const float4*)bo)[lane * 2 + j];
    v.x += bb.x; v.y += bb.y; v.z += bb.z; v.w += bb.w;
    s += v.x*v.x + v.y*v.y + v.z*v.z + v.w*v.w;
  }
#pragma unroll
  for (int m = 1; m < 64; m <<= 1) s += __shfl_xor(s, m);
  rstdy[row] = rsqrtf(s * (1.0f / C_N) + EPSN);
}

// ---------------- K8: final transpose + bias + norm + residual ----------------
__global__ __launch_bounds__(256) void final_kernel(
    const float* __restrict__ ytmp, const float* __restrict__ bo,
    const float* __restrict__ g2, const float* __restrict__ rstdy,
    const float* __restrict__ x, float* __restrict__ out)
{
  __shared__ float tile[32][33];
  int b = blockIdx.z, c0 = blockIdx.y * 32, p0 = blockIdx.x * 32;
  int tx = threadIdx.x & 31, ty = threadIdx.x >> 5;
#pragma unroll
  for (int j = 0; j < 4; ++j) {
    int p = ty + j * 8;
    tile[p][tx] = ytmp[((long)b * HW_N + p0 + p) * C_N + c0 + tx] + bo[c0 + tx];
  }
  __syncthreads();
#pragma unroll
  for (int j = 0; j < 4; ++j) {
    int c = ty + j * 8;
    long oidx = ((long)b * C_N + c0 + c) * HW_N + p0 + tx;
    out[oidx] = tile[tx][c] * rstdy[b * HW_N + p0 + tx] * g2[c0 + c] + x[oidx];
  }
}

// ---------------- launch ----------------
extern "C" void kernel_launch(void* const* d_in, const int* in_sizes, int n_in,
                              void* d_out, int out_size, void* d_ws, size_t ws_size,
                              hipStream_t stream) {
  const float* x   = (const float*)d_in[0];
  const float* ctx = (const float*)d_in[1];
  const float* Wq  = (const float*)d_in[2];
  const float* Wkv = (const float*)d_in[3];
  const float* Wo  = (const float*)d_in[4];
  const float* bo  = (const float*)d_in[5];
  const float* g   = (const float*)d_in[6];
  const float* g2  = (const float*)d_in[7];
  float* out = (float*)d_out;

  char* ws = (char*)d_ws;
  bf16*  Wqg   = (bf16*)(ws + 0);          //  512*512*2  = 524288
  bf16*  Wkvg  = (bf16*)(ws + 524288);     // 1024*512*2  = 1048576
  bf16*  Wob   = (bf16*)(ws + 1572864);    //  512*512*2  = 524288
  float* rstdx = (float*)(ws + 2097152);   // 8192*4      = 32768
  float* rstdy = (float*)(ws + 2129920);   // 8192*4      = 32768
  bf16*  xbf   = (bf16*)(ws + 2162688);    // 8*1024*512*2 = 8388608
  bf16*  cnbf  = (bf16*)(ws + 10551296);   // 8388608
  bf16*  qbf   = (bf16*)(ws + 18939904);   // 8388608
  bf16*  kvbf  = (bf16*)(ws + 27328512);   // 8*1024*1024*2 = 16777216
  bf16*  vT    = (bf16*)(ws + 44105728);   // 8388608
  bf16*  attno = (bf16*)(ws + 52494336);   // 8388608
  float* ytmp  = (float*)(ws + 2162688);   // aliases xbf+cnbf (dead by then)

  prep_weights<<<4096, 256, 0, stream>>>(Wq, Wkv, Wo, g, Wqg, Wkvg, Wob);
  rstd_ch_kernel<<<128, 256, 0, stream>>>(x, rstdx);
  xbf_kernel<<<dim3(32, 16, 8), 256, 0, stream>>>(x, rstdx, xbf);
  ctxnorm_kernel<<<2048, 256, 0, stream>>>(ctx, cnbf);

  // Q scale folds softmax's log2(e): 0.125 * 1.4426950408889634
  gemm_nt<0><<<dim3(64, 8), 256, 0, stream>>>(
      xbf, Wqg, qbf, nullptr, HID_N, C_N, 0.18033688011112042f);
  gemm_nt<1><<<dim3(64, 16), 256, 0, stream>>>(
      cnbf, Wkvg, kvbf, vT, 2 * HID_N, C_N, 1.0f);

  attn_fused<<<dim3(64, 8), 256, 0, stream>>>(qbf, kvbf, vT, attno);

  gemm_nt<2><<<dim3(64, 8), 256, 0, stream>>>(
      attno, Wob, ytmp, nullptr, C_N, HID_N, 1.0f);

  ystats_kernel<<<2048, 256, 0, stream>>>(ytmp, bo, rstdy);
  final_kernel<<<dim3(32, 16, 8), 256, 0, stream>>>(ytmp, bo, g2, rstdy, x, out);
}